// Round 10
// baseline (92.257 us; speedup 1.0000x reference)
//
#include <hip/hip_runtime.h>

#define BB 64
#define RR 100
#define CC 2048
#define HH 512

#define S_ELEMS ((size_t)BB * RR * CC)  // 13,107,200

// ws layout (float offsets)
#define WS_SM ((size_t)0)  // BB*CC = 131,072

// ---- kernel F: fused masks-reduce + feats row-sum + S write + Sm ----------
// (verbatim r5-validated body; plain stores — kernel boundary provides
// coherence.) grid (8 c-tiles of 256, 64 b), 256 threads.
__global__ __launch_bounds__(256) void kF(const float* __restrict__ feats,
                                          const float* __restrict__ masks,
                                          float* __restrict__ S,
                                          float* __restrict__ Sm) {
    __shared__ float stage[12544];  // phase1 scratch [256][8]; phase2 feats tile
    __shared__ float sM[RR * 8];
    __shared__ float sMbar[8];
    int b = blockIdx.y;
    int ctile = blockIdx.x;
    int t = threadIdx.x;

    // phase 1: per-r column sums of masks[b,r,:,:]
    float m[8] = {0.f, 0.f, 0.f, 0.f, 0.f, 0.f, 0.f, 0.f};
    if (t < RR) {
        const float* p = masks + ((size_t)b * RR + t) * 49;
#pragma unroll
        for (int i = 0; i < 7; ++i)
#pragma unroll
            for (int k = 0; k < 7; ++k) m[k] += p[i * 7 + k];
    }
#pragma unroll
    for (int k = 0; k < 8; ++k) stage[t * 8 + k] = m[k];
    if (t < RR) {
#pragma unroll
        for (int k = 0; k < 8; ++k) sM[t * 8 + k] = m[k];
    }
    __syncthreads();
    if (t < 8) {
        float s = 0.f;
        for (int r = 0; r < RR; ++r) s += stage[r * 8 + t];
        sMbar[t] = s * (1.0f / RR);
    }
    __syncthreads();  // stage reads done; sMbar/sM visible

    // phase 2: stage feats[b, c0..c0+255, :, :] (50 KB) and row-sum
    const size_t base = ((size_t)b * CC + (size_t)ctile * 256) * 49;
    const float4* src = (const float4*)(feats + base);
    float4* dst = (float4*)stage;
#pragma unroll
    for (int i = 0; i < 13; ++i) {
        int idx = t + i * 256;
        if (idx < 3136) dst[idx] = src[idx];
    }
    __syncthreads();
    const float* my = stage + t * 49;
    float f0 = 0.f, f1 = 0.f, f2 = 0.f, f3 = 0.f, f4 = 0.f, f5 = 0.f, f6 = 0.f;
#pragma unroll
    for (int j = 0; j < 7; ++j) {
        f0 += my[0 * 7 + j]; f1 += my[1 * 7 + j]; f2 += my[2 * 7 + j];
        f3 += my[3 * 7 + j]; f4 += my[4 * 7 + j]; f5 += my[5 * 7 + j];
        f6 += my[6 * 7 + j];
    }
    const float inv = 1.0f / 49.0f;
    int c = ctile * 256 + t;
    float sm = f0 * sMbar[0] + f1 * sMbar[1] + f2 * sMbar[2] + f3 * sMbar[3] +
               f4 * sMbar[4] + f5 * sMbar[5] + f6 * sMbar[6];
    Sm[(size_t)b * CC + c] = sm * inv;

    // phase 3: S[b,r,c] = (1/49) dot7(M[b,r], f)
    float* Sp = S + (size_t)b * RR * CC + c;
#pragma unroll 4
    for (int r = 0; r < RR; ++r) {
        float4 m0 = *(const float4*)&sM[r * 8];
        float4 m1 = *(const float4*)&sM[r * 8 + 4];
        float v = m0.x * f0 + m0.y * f1 + m0.z * f2 + m0.w * f3 +
                  m1.x * f4 + m1.y * f5 + m1.z * f6;
        Sp[(size_t)r * CC] = v * inv;
    }
}

// ---- kernel H: direct GEMM out = Sm @ [W1;W2]^T + bias --------------------
// grid 256, block 256. Block owns 4 h-rows x all 64 b. Within a wave all 64
// lanes share one h -> W loads are wave-uniform broadcasts (W read once from
// HBM, 8 MB). Sm (512 KB) is L2-resident; per-lane row gather with L1 reuse
// across k. No split-K, no partials, no sync.
__global__ __launch_bounds__(256) void kH(const float* __restrict__ Sm,
                                          const float* __restrict__ W1,
                                          const float* __restrict__ b1,
                                          const float* __restrict__ W2,
                                          const float* __restrict__ b2,
                                          float* __restrict__ out) {
    int t = threadIdx.x;
    int b = t & 63;
    int hl = t >> 6;              // 0..3 (one h per wave)
    int h = blockIdx.x * 4 + hl;  // 0..1023 over concat [h0|c0]
    int which = h >> 9;
    int hh = h & 511;
    const float* W = which ? W2 : W1;
    const float* bias = which ? b2 : b1;

    const float4* sp = (const float4*)(Sm + (size_t)b * CC);
    const float4* wp = (const float4*)(W + (size_t)hh * CC);
    float a0 = 0.f, a1 = 0.f, a2 = 0.f, a3 = 0.f;
#pragma unroll 4
    for (int k = 0; k < CC / 4; ++k) {
        float4 s = sp[k];
        float4 w = wp[k];
        a0 += s.x * w.x; a1 += s.y * w.y; a2 += s.z * w.z; a3 += s.w * w.w;
    }
    float acc = (a0 + a1) + (a2 + a3) + bias[hh];
    out[S_ELEMS + (size_t)which * ((size_t)BB * HH) + (size_t)b * HH + hh] = acc;
}

extern "C" void kernel_launch(void* const* d_in, const int* in_sizes, int n_in,
                              void* d_out, int out_size, void* d_ws, size_t ws_size,
                              hipStream_t stream) {
    const float* feats = (const float*)d_in[0];
    const float* masks = (const float*)d_in[1];
    const float* W1 = (const float*)d_in[2];
    const float* b1 = (const float*)d_in[3];
    const float* W2 = (const float*)d_in[4];
    const float* b2 = (const float*)d_in[5];
    float* out = (float*)d_out;
    float* ws = (float*)d_ws;
    float* Sm = ws + WS_SM;

    kF<<<dim3(8, 64), 256, 0, stream>>>(feats, masks, out, Sm);
    kH<<<256, 256, 0, stream>>>(Sm, W1, b1, W2, b2, out);
}

// Round 11
// 42.828 us; speedup vs baseline: 2.1541x; 2.1541x over previous
//
#include <hip/hip_runtime.h>

#define BB 64
#define RR 100
#define CC 2048
#define HH 512

#define S_ELEMS ((size_t)BB * RR * CC)  // 13,107,200

// ws layout (float offsets)
#define WS_SM   ((size_t)0)                  // BB*CC = 131,072
#define WS_PART (WS_SM + (size_t)BB * CC)    // KSPLIT*BB*1024 = 2,097,152

#define KSPLIT 32
#define KCHUNK (CC / KSPLIT)  // 64
#define KC 32

// ---- kernel F: fused masks-reduce + feats row-sum + S write + Sm ----------
// (verbatim r5/r10-validated; measured ~13 us, at its ~12.7 us traffic floor)
__global__ __launch_bounds__(256) void kF(const float* __restrict__ feats,
                                          const float* __restrict__ masks,
                                          float* __restrict__ S,
                                          float* __restrict__ Sm) {
    __shared__ float stage[12544];  // phase1 scratch [256][8]; phase2 feats tile
    __shared__ float sM[RR * 8];
    __shared__ float sMbar[8];
    int b = blockIdx.y;
    int ctile = blockIdx.x;
    int t = threadIdx.x;

    float m[8] = {0.f, 0.f, 0.f, 0.f, 0.f, 0.f, 0.f, 0.f};
    if (t < RR) {
        const float* p = masks + ((size_t)b * RR + t) * 49;
#pragma unroll
        for (int i = 0; i < 7; ++i)
#pragma unroll
            for (int k = 0; k < 7; ++k) m[k] += p[i * 7 + k];
    }
#pragma unroll
    for (int k = 0; k < 8; ++k) stage[t * 8 + k] = m[k];
    if (t < RR) {
#pragma unroll
        for (int k = 0; k < 8; ++k) sM[t * 8 + k] = m[k];
    }
    __syncthreads();
    if (t < 8) {
        float s = 0.f;
        for (int r = 0; r < RR; ++r) s += stage[r * 8 + t];
        sMbar[t] = s * (1.0f / RR);
    }
    __syncthreads();  // stage reads done; sMbar/sM visible

    const size_t base = ((size_t)b * CC + (size_t)ctile * 256) * 49;
    const float4* src = (const float4*)(feats + base);
    float4* dst = (float4*)stage;
#pragma unroll
    for (int i = 0; i < 13; ++i) {
        int idx = t + i * 256;
        if (idx < 3136) dst[idx] = src[idx];
    }
    __syncthreads();
    const float* my = stage + t * 49;
    float f0 = 0.f, f1 = 0.f, f2 = 0.f, f3 = 0.f, f4 = 0.f, f5 = 0.f, f6 = 0.f;
#pragma unroll
    for (int j = 0; j < 7; ++j) {
        f0 += my[0 * 7 + j]; f1 += my[1 * 7 + j]; f2 += my[2 * 7 + j];
        f3 += my[3 * 7 + j]; f4 += my[4 * 7 + j]; f5 += my[5 * 7 + j];
        f6 += my[6 * 7 + j];
    }
    const float inv = 1.0f / 49.0f;
    int c = ctile * 256 + t;
    float sm = f0 * sMbar[0] + f1 * sMbar[1] + f2 * sMbar[2] + f3 * sMbar[3] +
               f4 * sMbar[4] + f5 * sMbar[5] + f6 * sMbar[6];
    Sm[(size_t)b * CC + c] = sm * inv;

    float* Sp = S + (size_t)b * RR * CC + c;
#pragma unroll 4
    for (int r = 0; r < RR; ++r) {
        float4 m0 = *(const float4*)&sM[r * 8];
        float4 m1 = *(const float4*)&sM[r * 8 + 4];
        float v = m0.x * f0 + m0.y * f1 + m0.z * f2 + m0.w * f3 +
                  m1.x * f4 + m1.y * f5 + m1.z * f6;
        Sp[(size_t)r * CC] = v * inv;
    }
}

// ---- kernel D1: split-K GEMM partials --------------------------------------
// Verbatim round-3 kE GEMM branch (machine-validated there), lifted to a
// standalone 128-block kernel. bid mapping identical: ht=bid&3, ks=bid>>2.
__global__ __launch_bounds__(256) void kD1(const float* __restrict__ Sm,
                                           const float* __restrict__ W1,
                                           const float* __restrict__ W2,
                                           float* __restrict__ part) {
    __shared__ float smem[10496];
    int t = threadIdx.x;
    int ht = blockIdx.x & 3;   // 0..3 -> 256-h tile over concat [W1;W2]
    int ks = blockIdx.x >> 2;  // 0..31
    const float* W = (ht < 2) ? W1 : W2;
    int hrow0 = (ht & 1) * 256;
    float* sW = smem;          // [cc][260]
    float* sS = smem + 8320;   // [cc][68]

    float acc[8][8];
#pragma unroll
    for (int i = 0; i < 8; ++i)
#pragma unroll
        for (int j = 0; j < 8; ++j) acc[i][j] = 0.f;

    int bg = t & 7;   // 8 groups x 8 b
    int hg = t >> 3;  // 32 groups x 8 h

    for (int sub = 0; sub < KCHUNK / KC; ++sub) {
        int c0 = ks * KCHUNK + sub * KC;
        for (int i = t; i < 256 * KC; i += 256) {
            int h = i >> 5, cc = i & 31;
            sW[cc * 260 + h] = W[(size_t)(hrow0 + h) * CC + c0 + cc];
        }
        for (int i = t; i < 64 * KC; i += 256) {
            int bb = i >> 5, cc = i & 31;
            sS[cc * 68 + bb] = Sm[(size_t)bb * CC + c0 + cc];
        }
        __syncthreads();
        for (int cc = 0; cc < KC; ++cc) {
            float4 s0 = *(const float4*)&sS[cc * 68 + bg * 8];
            float4 s1 = *(const float4*)&sS[cc * 68 + bg * 8 + 4];
            float4 w0 = *(const float4*)&sW[cc * 260 + hg * 8];
            float4 w1 = *(const float4*)&sW[cc * 260 + hg * 8 + 4];
            float fs[8] = {s0.x, s0.y, s0.z, s0.w, s1.x, s1.y, s1.z, s1.w};
            float fw[8] = {w0.x, w0.y, w0.z, w0.w, w1.x, w1.y, w1.z, w1.w};
#pragma unroll
            for (int i = 0; i < 8; ++i)
#pragma unroll
                for (int j = 0; j < 8; ++j) acc[i][j] += fs[i] * fw[j];
        }
        __syncthreads();
    }

    int hglobal = ht * 256 + hg * 8;  // 0..1023
    float* pp = part + (size_t)ks * (BB * 1024);
#pragma unroll
    for (int i = 0; i < 8; ++i) {
        int bb = bg * 8 + i;
        float* o = pp + (size_t)bb * 1024 + hglobal;
        *(float4*)(o) = make_float4(acc[i][0], acc[i][1], acc[i][2], acc[i][3]);
        *(float4*)(o + 4) = make_float4(acc[i][4], acc[i][5], acc[i][6], acc[i][7]);
    }
}

// ---- kernel D2: out = sum_ks part + bias (verbatim round-3, validated) ----
__global__ __launch_bounds__(256) void kD2(const float* __restrict__ part,
                                           const float* __restrict__ b1,
                                           const float* __restrict__ b2,
                                           float* __restrict__ out) {
    int idx = blockIdx.x * 256 + threadIdx.x;  // 0..65535
    int b = idx >> 10;
    int h = idx & 1023;
    float s = (h < HH) ? b1[h] : b2[h - HH];
#pragma unroll
    for (int ks = 0; ks < KSPLIT; ++ks) s += part[(size_t)ks * (BB * 1024) + idx];
    int which = h >> 9;
    out[S_ELEMS + (size_t)which * ((size_t)BB * HH) + (size_t)b * HH + (h & 511)] = s;
}

extern "C" void kernel_launch(void* const* d_in, const int* in_sizes, int n_in,
                              void* d_out, int out_size, void* d_ws, size_t ws_size,
                              hipStream_t stream) {
    const float* feats = (const float*)d_in[0];
    const float* masks = (const float*)d_in[1];
    const float* W1 = (const float*)d_in[2];
    const float* b1 = (const float*)d_in[3];
    const float* W2 = (const float*)d_in[4];
    const float* b2 = (const float*)d_in[5];
    float* out = (float*)d_out;
    float* ws = (float*)d_ws;
    float* Sm = ws + WS_SM;
    float* part = ws + WS_PART;

    kF<<<dim3(8, 64), 256, 0, stream>>>(feats, masks, out, Sm);
    kD1<<<128, 256, 0, stream>>>(Sm, W1, W2, part);
    kD2<<<256, 256, 0, stream>>>(part, b1, b2, out);
}